// Round 3
// baseline (4279.547 us; speedup 1.0000x reference)
//
#include <hip/hip_runtime.h>
#include <hip/hip_bf16.h>
#include <cstddef>

// Problem constants: BS=4, SEQ=2048, EMB=512, BD=8, H=64; tokens M=8192.

// ---------------------------------------------------------------------------
// Tiled fp32 GEMM:  C = op(A @ B^T + bias)
//   A: (M,K) row-major, B: (N,K) row-major, bias: (N)
// MODE 1: relu, row-major C (M,N)
// MODE 2: write BLKT scan layout [b, h, s, 64]  (global_row = roff + row)
// MODE 3: write VT scan layout  [b, h, s, 8]
// Tile 128x128, BK=8, 256 threads, 8x8 micro-tile per thread.
// ---------------------------------------------------------------------------
template<int MODE>
__global__ __launch_bounds__(256)
void gemm_nt(const float* __restrict__ A, const float* __restrict__ B,
             const float* __restrict__ bias, float* __restrict__ C,
             int M, int N, int K, int roff) {
  __shared__ float As[8][128];
  __shared__ float Bs[8][128];
  const int tid = threadIdx.x;
  const int tx = tid & 15, ty = tid >> 4;
  const int m0 = blockIdx.y << 7, n0 = blockIdx.x << 7;
  const int lrow = tid >> 1, lk = (tid & 1) << 2;
  const float* Ap = A + (size_t)(m0 + lrow) * K + lk;
  const float* Bp = B + (size_t)(n0 + lrow) * K + lk;

  float acc[8][8];
#pragma unroll
  for (int r = 0; r < 8; ++r)
#pragma unroll
    for (int c = 0; c < 8; ++c) acc[r][c] = 0.f;

  for (int k0 = 0; k0 < K; k0 += 8) {
    float4 av = *(const float4*)(Ap + k0);
    float4 bv = *(const float4*)(Bp + k0);
    __syncthreads();
    As[lk + 0][lrow] = av.x; As[lk + 1][lrow] = av.y;
    As[lk + 2][lrow] = av.z; As[lk + 3][lrow] = av.w;
    Bs[lk + 0][lrow] = bv.x; Bs[lk + 1][lrow] = bv.y;
    Bs[lk + 2][lrow] = bv.z; Bs[lk + 3][lrow] = bv.w;
    __syncthreads();
#pragma unroll
    for (int kk = 0; kk < 8; ++kk) {
      float a[8], b[8];
      *(float4*)&a[0] = *(const float4*)&As[kk][ty << 3];
      *(float4*)&a[4] = *(const float4*)&As[kk][(ty << 3) + 4];
      *(float4*)&b[0] = *(const float4*)&Bs[kk][tx << 3];
      *(float4*)&b[4] = *(const float4*)&Bs[kk][(tx << 3) + 4];
#pragma unroll
      for (int r = 0; r < 8; ++r)
#pragma unroll
        for (int c = 0; c < 8; ++c)
          acc[r][c] += a[r] * b[c];
    }
  }

  const int nb = n0 + (tx << 3);
  float bz[8];
  *(float4*)&bz[0] = *(const float4*)&bias[nb];
  *(float4*)&bz[4] = *(const float4*)&bias[nb + 4];

#pragma unroll
  for (int r = 0; r < 8; ++r) {
    const int row = m0 + (ty << 3) + r;
    float v[8];
#pragma unroll
    for (int c = 0; c < 8; ++c) {
      float t = acc[r][c] + bz[c];
      if (MODE == 1) t = fmaxf(t, 0.f);
      v[c] = t;
    }
    float* dst;
    if (MODE == 1) {
      dst = C + (size_t)row * N + nb;
    } else {
      const int grow = roff + row;
      const int bb = grow >> 11, s = grow & 2047;  // SEQ=2048
      if (MODE == 2) {
        const int h = nb >> 6, r64 = nb & 63;
        dst = C + (((size_t)(bb * 64 + h) * 2048 + s) * 64 + r64);
      } else {
        const int h = nb >> 3;
        dst = C + (((size_t)(bb * 64 + h) * 2048 + s) * 8);
      }
    }
    *(float4*)dst = *(float4*)&v[0];
    *(float4*)(dst + 4) = *(float4*)&v[4];
  }
}

// ---------------------------------------------------------------------------
// Block normalization in place on BLKT ([b,h,s,64]); one wave per (b,h,s).
// lane = i*8+j. x -= mean_i; norm_j = (sum_i |x|^1.2)^(1/1.2); x /= max_j norm_j.
// ---------------------------------------------------------------------------
__global__ __launch_bounds__(256)
void norm_kernel(float* __restrict__ BLKT) {
  const int task = (blockIdx.x << 2) + (threadIdx.x >> 6);
  const int lane = threadIdx.x & 63;
  float* p = BLKT + (size_t)task * 64;
  float x = p[lane];
  float m = x;
  m += __shfl_xor(m, 8);
  m += __shfl_xor(m, 16);
  m += __shfl_xor(m, 32);
  x -= m * 0.125f;
  float ax = fabsf(x);
  float t = exp2f(1.2f * log2f(ax));  // |x|^1.2 ; log2f(0)=-inf -> exp2f=0, OK
  t += __shfl_xor(t, 8);
  t += __shfl_xor(t, 16);
  t += __shfl_xor(t, 32);
  float nrm = exp2f((1.0f / 1.2f) * log2f(t));
  float mx = nrm;
  mx = fmaxf(mx, __shfl_xor(mx, 1));
  mx = fmaxf(mx, __shfl_xor(mx, 2));
  mx = fmaxf(mx, __shfl_xor(mx, 4));
  p[lane] = x / mx;
}

// ---------------------------------------------------------------------------
// Sequential affine scan per (b,h): y_{s+1} = A_s y_s + v_s ; out[s] = y_{s+1}
// One wave per (b,h). Chunked double-buffered LDS; staging is plain
// float4 global loads -> registers -> ds_write (no builtins, no inline asm).
// Prefetch of chunk c+1 is issued before computing chunk c; the ds_write of
// the prefetched registers happens after the compute, so the compiler's
// vmcnt wait lands there -> global latency hidden under 32 scan steps.
// Single wave per block: DS pipe is in-order, no barriers needed.
// ---------------------------------------------------------------------------
#define SCH 32
__global__ __launch_bounds__(64)
void scan_kernel(const float* __restrict__ BLKT, const float* __restrict__ VT,
                 const float* __restrict__ a0, float* __restrict__ out) {
  __shared__ __align__(16) float Abuf[2][SCH * 64];
  __shared__ __align__(16) float vbuf[2][SCH * 8];
  const int bid = blockIdx.x;  // b*64 + h
  const int b = bid >> 6, h = bid & 63;
  const int lane = threadIdx.x;
  const float* Ab = BLKT + (size_t)bid * (2048 * 64);
  const float* Vb = VT + (size_t)bid * (2048 * 8);
  float* ob = out + (size_t)b * (2048 * 512) + h * 8;

  float y = a0[h * 8 + (lane & 7)];  // a0 broadcast over batch

  float4 ra[8];
  float4 rv;
  auto loadc = [&](int c) {
    const float* sA = Ab + (size_t)c * (SCH * 64);
#pragma unroll
    for (int q = 0; q < 8; ++q) ra[q] = *(const float4*)(sA + q * 256 + lane * 4);
    rv = *(const float4*)(Vb + (size_t)c * (SCH * 8) + lane * 4);
  };
  auto store_lds = [&](int slot) {
#pragma unroll
    for (int q = 0; q < 8; ++q)
      *(float4*)&Abuf[slot][q * 256 + lane * 4] = ra[q];
    *(float4*)&vbuf[slot][lane * 4] = rv;
  };

  loadc(0);
  store_lds(0);
  int cur = 0;
  const int NC = 2048 / SCH;
  for (int c = 0; c < NC; ++c) {
    if (c + 1 < NC) loadc(c + 1);  // prefetch next chunk into registers
#pragma unroll
    for (int s = 0; s < SCH; ++s) {
      float a = Abuf[cur][s * 64 + lane];   // A[i][j], lane = i*8+j
      float p = a * y;                      // y holds y_prev[j], j = lane&7
      p += __shfl_xor(p, 1);
      p += __shfl_xor(p, 2);
      p += __shfl_xor(p, 4);                // row-group i sums over j
      float yn = p + vbuf[cur][s * 8 + (lane >> 3)];
      if ((lane & 7) == 0)
        ob[(size_t)(c * SCH + s) * 512 + (lane >> 3)] = yn;
      y = __shfl(yn, (lane & 7) << 3);      // redistribute y[j] to all rows
    }
    if (c + 1 < NC) store_lds(cur ^ 1);     // write prefetched regs to LDS
    cur ^= 1;
  }
}

// ---------------------------------------------------------------------------
extern "C" void kernel_launch(void* const* d_in, const int* in_sizes, int n_in,
                              void* d_out, int out_size, void* d_ws, size_t ws_size,
                              hipStream_t stream) {
  const float* x  = (const float*)d_in[0];
  const float* W1 = (const float*)d_in[1];
  const float* b1 = (const float*)d_in[2];
  const float* W2 = (const float*)d_in[3];
  const float* b2 = (const float*)d_in[4];
  const float* V1 = (const float*)d_in[5];
  const float* c1 = (const float*)d_in[6];
  const float* V2 = (const float*)d_in[7];
  const float* c2 = (const float*)d_in[8];
  const float* a0 = (const float*)d_in[9];
  float* out = (float*)d_out;
  float* ws = (float*)d_ws;

  // Workspace layout (floats), total 46,137,344 floats = 184.5 MB:
  float* BLKT = ws;                       // 33554432  [b,h,s,64]
  float* VT   = ws + 33554432ull;         // 4194304   [b,h,s,8]
  float* H1c  = ws + 37748736ull;         // 8388608   (2048 x 4096 chunk)
  float* HV   = H1c;                      // alias (used after H1c chunks done)

  dim3 blk(256);
  // MLP in 4 chunks of 2048 token-rows to bound workspace
  for (int c = 0; c < 4; ++c) {
    const float* xc = x + (size_t)c * 2048 * 512;
    // H1c = relu(xc @ W1^T + b1)          M=2048 N=4096 K=512
    gemm_nt<1><<<dim3(32, 16), blk, 0, stream>>>(xc, W1, b1, H1c, 2048, 4096, 512, 0);
    // BLKT rows = H1c @ W2^T + b2         M=2048 N=4096 K=4096
    gemm_nt<2><<<dim3(32, 16), blk, 0, stream>>>(H1c, W2, b2, BLKT, 2048, 4096, 4096, c * 2048);
  }
  // normalize 8x8 blocks in place
  norm_kernel<<<131072, 256, 0, stream>>>(BLKT);
  // HV = relu(x @ V1^T + c1)              M=8192 N=512 K=512
  gemm_nt<1><<<dim3(4, 64), blk, 0, stream>>>(x, V1, c1, HV, 8192, 512, 512, 0);
  // VT = HV @ V2^T + c2 (scan layout)     M=8192 N=512 K=512
  gemm_nt<3><<<dim3(4, 64), blk, 0, stream>>>(HV, V2, c2, VT, 8192, 512, 512, 0);
  // sequential affine scan -> out
  scan_kernel<<<256, 64, 0, stream>>>(BLKT, VT, a0, out);
}

// Round 4
// 1499.655 us; speedup vs baseline: 2.8537x; 2.8537x over previous
//
#include <hip/hip_runtime.h>
#include <hip/hip_bf16.h>
#include <cstddef>

// Problem constants: BS=4, SEQ=2048, EMB=512, BD=8, H=64; tokens M=8192.

typedef _Float16 f16;
typedef _Float16 f16x4 __attribute__((ext_vector_type(4)));
typedef _Float16 f16x8 __attribute__((ext_vector_type(8)));
typedef float f32x4 __attribute__((ext_vector_type(4)));

#define LDP 40  // padded LDS stride in f16 (80 B = 5*16B: 16B-aligned, ~2-way banks)

// ---------------------------------------------------------------------------
// Split-f16 MFMA GEMM:  C = op(A @ B^T + bias)
//   A: (M,K), B: (N,K) row-major.  Internally A,B split to f16 hi+lo;
//   product via 3x mfma_f32_16x16x32_f16 (hi*hi + hi*lo + lo*hi), fp32 acc.
// AFMT 0: A is fp32 (convert during staging)
// AFMT 1: A is packed u32 per element: low16 = hi f16 bits, high16 = lo f16
// MODE 0: relu, split, store packed u32 [M][N] (feeds AFMT=1 consumer)
// MODE 2: fp32 store to BLKT scan layout [b,h,s,64] (token row = roff+row)
// MODE 3: fp32 store to VT scan layout [b,h,s,8]
// Tile 128x128, BK=32, 256 threads = 4 waves, each wave 64x64 output.
// ---------------------------------------------------------------------------
__device__ inline void stage_f32(const float* __restrict__ src, int ldk, int k0,
                                 f16* shi, f16* slo, int tid) {
  const int row = tid >> 1, kb = (tid & 1) << 4;
  const float* p = src + (size_t)row * ldk + k0 + kb;
#pragma unroll
  for (int q = 0; q < 4; ++q) {
    float4 v = *(const float4*)(p + q * 4);
    f16x4 h, l;
    h.x = (f16)v.x; l.x = (f16)(v.x - (float)h.x);
    h.y = (f16)v.y; l.y = (f16)(v.y - (float)h.y);
    h.z = (f16)v.z; l.z = (f16)(v.z - (float)h.z);
    h.w = (f16)v.w; l.w = (f16)(v.w - (float)h.w);
    *(f16x4*)&shi[row * LDP + kb + q * 4] = h;
    *(f16x4*)&slo[row * LDP + kb + q * 4] = l;
  }
}

__device__ inline void stage_pk(const unsigned int* __restrict__ src, int ldk, int k0,
                                f16* shi, f16* slo, int tid) {
  const int row = tid >> 1, kb = (tid & 1) << 4;
  const unsigned int* p = src + (size_t)row * ldk + k0 + kb;
#pragma unroll
  for (int q = 0; q < 4; ++q) {
    uint4 v = *(const uint4*)(p + q * 4);
    ushort4 hu, lu;
    hu.x = (unsigned short)(v.x & 0xffff); lu.x = (unsigned short)(v.x >> 16);
    hu.y = (unsigned short)(v.y & 0xffff); lu.y = (unsigned short)(v.y >> 16);
    hu.z = (unsigned short)(v.z & 0xffff); lu.z = (unsigned short)(v.z >> 16);
    hu.w = (unsigned short)(v.w & 0xffff); lu.w = (unsigned short)(v.w >> 16);
    *(ushort4*)&shi[row * LDP + kb + q * 4] = hu;
    *(ushort4*)&slo[row * LDP + kb + q * 4] = lu;
  }
}

template<int AFMT, int MODE>
__global__ __launch_bounds__(256)
void gemm_mfma(const void* __restrict__ Av, const float* __restrict__ B,
               const float* __restrict__ bias, void* __restrict__ Ov,
               int M, int N, int K, int roff) {
  __shared__ f16 sAhi[128 * LDP];
  __shared__ f16 sAlo[128 * LDP];
  __shared__ f16 sBhi[128 * LDP];
  __shared__ f16 sBlo[128 * LDP];
  const int tid = threadIdx.x;
  const int m0 = blockIdx.y << 7, n0 = blockIdx.x << 7;
  const int lane = tid & 63, wid = tid >> 6;
  const int wr = wid >> 1, wc = wid & 1;

  f32x4 acc[4][4];
#pragma unroll
  for (int m = 0; m < 4; ++m)
#pragma unroll
    for (int n = 0; n < 4; ++n) acc[m][n] = (f32x4)0.f;

  const int fr = lane & 15, fk = (lane >> 4) << 3;

  for (int k0 = 0; k0 < K; k0 += 32) {
    __syncthreads();
    if (AFMT == 0)
      stage_f32((const float*)Av + (size_t)m0 * K, K, k0, sAhi, sAlo, tid);
    else
      stage_pk((const unsigned int*)Av + (size_t)m0 * K, K, k0, sAhi, sAlo, tid);
    stage_f32(B + (size_t)n0 * K, K, k0, sBhi, sBlo, tid);
    __syncthreads();

    f16x8 ah[4], al[4], bh[4], bl[4];
#pragma unroll
    for (int m = 0; m < 4; ++m) {
      const int r = wr * 64 + m * 16 + fr;
      ah[m] = *(const f16x8*)&sAhi[r * LDP + fk];
      al[m] = *(const f16x8*)&sAlo[r * LDP + fk];
    }
#pragma unroll
    for (int n = 0; n < 4; ++n) {
      const int r = wc * 64 + n * 16 + fr;
      bh[n] = *(const f16x8*)&sBhi[r * LDP + fk];
      bl[n] = *(const f16x8*)&sBlo[r * LDP + fk];
    }
#pragma unroll
    for (int m = 0; m < 4; ++m)
#pragma unroll
      for (int n = 0; n < 4; ++n) {
        acc[m][n] = __builtin_amdgcn_mfma_f32_16x16x32_f16(ah[m], bh[n], acc[m][n], 0, 0, 0);
        acc[m][n] = __builtin_amdgcn_mfma_f32_16x16x32_f16(ah[m], bl[n], acc[m][n], 0, 0, 0);
        acc[m][n] = __builtin_amdgcn_mfma_f32_16x16x32_f16(al[m], bh[n], acc[m][n], 0, 0, 0);
      }
  }

  // Epilogue. D frag (m,n): col = n0+wc*64+n*16+(lane&15),
  //                         row = m0+wr*64+m*16+(lane>>4)*4+r
  const int fq = lane >> 4;
  float bz[4];
#pragma unroll
  for (int n = 0; n < 4; ++n) bz[n] = bias[n0 + wc * 64 + n * 16 + fr];

#pragma unroll
  for (int m = 0; m < 4; ++m)
#pragma unroll
    for (int n = 0; n < 4; ++n) {
      const int col = n0 + wc * 64 + n * 16 + fr;
#pragma unroll
      for (int r = 0; r < 4; ++r) {
        const int row = m0 + wr * 64 + m * 16 + fq * 4 + r;
        float v = acc[m][n][r] + bz[n];
        if (MODE == 0) {
          v = fmaxf(v, 0.f);
          f16 h = (f16)v;
          f16 l = (f16)(v - (float)h);
          unsigned pk = ((unsigned)__builtin_bit_cast(unsigned short, l) << 16)
                      | (unsigned)__builtin_bit_cast(unsigned short, h);
          ((unsigned*)Ov)[(size_t)row * N + col] = pk;
        } else {
          const int grow = roff + row;
          const int bb = grow >> 11, s = grow & 2047;  // SEQ=2048
          if (MODE == 2) {
            ((float*)Ov)[(((size_t)(bb * 64 + (col >> 6)) * 2048 + s) << 6) + (col & 63)] = v;
          } else {
            ((float*)Ov)[(((size_t)(bb * 64 + (col >> 3)) * 2048 + s) << 3) + (col & 7)] = v;
          }
        }
      }
    }
}

// ---------------------------------------------------------------------------
// Block normalization in place on BLKT ([b,h,s,64]); one wave per (b,h,s).
// lane = i*8+j. x -= mean_i; norm_j = (sum_i |x|^1.2)^(1/1.2); x /= max_j norm_j.
// ---------------------------------------------------------------------------
__global__ __launch_bounds__(256)
void norm_kernel(float* __restrict__ BLKT) {
  const int task = (blockIdx.x << 2) + (threadIdx.x >> 6);
  const int lane = threadIdx.x & 63;
  float* p = BLKT + (size_t)task * 64;
  float x = p[lane];
  float m = x;
  m += __shfl_xor(m, 8);
  m += __shfl_xor(m, 16);
  m += __shfl_xor(m, 32);
  x -= m * 0.125f;
  float ax = fabsf(x);
  float t = exp2f(1.2f * log2f(ax));  // |x|^1.2 ; log2f(0)=-inf -> exp2f=0, OK
  t += __shfl_xor(t, 8);
  t += __shfl_xor(t, 16);
  t += __shfl_xor(t, 32);
  float nrm = exp2f((1.0f / 1.2f) * log2f(t));
  float mx = nrm;
  mx = fmaxf(mx, __shfl_xor(mx, 1));
  mx = fmaxf(mx, __shfl_xor(mx, 2));
  mx = fmaxf(mx, __shfl_xor(mx, 4));
  p[lane] = x / mx;
}

// ---------------------------------------------------------------------------
// Sequential affine scan per (b,h): y_{s+1} = A_s y_s + v_s ; out[s] = y_{s+1}
// One wave per (b,h). Chunked double-buffered LDS; prefetch chunk c+1 into
// registers before computing chunk c; ds_write after compute (vmcnt hidden).
// ---------------------------------------------------------------------------
#define SCH 32
__global__ __launch_bounds__(64)
void scan_kernel(const float* __restrict__ BLKT, const float* __restrict__ VT,
                 const float* __restrict__ a0, float* __restrict__ out) {
  __shared__ __align__(16) float Abuf[2][SCH * 64];
  __shared__ __align__(16) float vbuf[2][SCH * 8];
  const int bid = blockIdx.x;  // b*64 + h
  const int b = bid >> 6, h = bid & 63;
  const int lane = threadIdx.x;
  const float* Ab = BLKT + (size_t)bid * (2048 * 64);
  const float* Vb = VT + (size_t)bid * (2048 * 8);
  float* ob = out + (size_t)b * (2048 * 512) + h * 8;

  float y = a0[h * 8 + (lane & 7)];  // a0 broadcast over batch

  float4 ra[8];
  float4 rv;
  auto loadc = [&](int c) {
    const float* sA = Ab + (size_t)c * (SCH * 64);
#pragma unroll
    for (int q = 0; q < 8; ++q) ra[q] = *(const float4*)(sA + q * 256 + lane * 4);
    rv = *(const float4*)(Vb + (size_t)c * (SCH * 8) + lane * 4);
  };
  auto store_lds = [&](int slot) {
#pragma unroll
    for (int q = 0; q < 8; ++q)
      *(float4*)&Abuf[slot][q * 256 + lane * 4] = ra[q];
    *(float4*)&vbuf[slot][lane * 4] = rv;
  };

  loadc(0);
  store_lds(0);
  int cur = 0;
  const int NC = 2048 / SCH;
  for (int c = 0; c < NC; ++c) {
    if (c + 1 < NC) loadc(c + 1);  // prefetch next chunk into registers
#pragma unroll
    for (int s = 0; s < SCH; ++s) {
      float a = Abuf[cur][s * 64 + lane];   // A[i][j], lane = i*8+j
      float p = a * y;                      // y holds y_prev[j], j = lane&7
      p += __shfl_xor(p, 1);
      p += __shfl_xor(p, 2);
      p += __shfl_xor(p, 4);                // row-group i sums over j
      float yn = p + vbuf[cur][s * 8 + (lane >> 3)];
      if ((lane & 7) == 0)
        ob[(size_t)(c * SCH + s) * 512 + (lane >> 3)] = yn;
      y = __shfl(yn, (lane & 7) << 3);      // redistribute y[j] to all rows
    }
    if (c + 1 < NC) store_lds(cur ^ 1);     // write prefetched regs to LDS
    cur ^= 1;
  }
}

// ---------------------------------------------------------------------------
extern "C" void kernel_launch(void* const* d_in, const int* in_sizes, int n_in,
                              void* d_out, int out_size, void* d_ws, size_t ws_size,
                              hipStream_t stream) {
  const float* x  = (const float*)d_in[0];
  const float* W1 = (const float*)d_in[1];
  const float* b1 = (const float*)d_in[2];
  const float* W2 = (const float*)d_in[3];
  const float* b2 = (const float*)d_in[4];
  const float* V1 = (const float*)d_in[5];
  const float* c1 = (const float*)d_in[6];
  const float* V2 = (const float*)d_in[7];
  const float* c2 = (const float*)d_in[8];
  const float* a0 = (const float*)d_in[9];
  float* out = (float*)d_out;
  float* ws = (float*)d_ws;

  // Workspace (floats), total 46,137,344 floats = 184.5 MB (known-safe):
  float* BLKT = ws;                        // 33554432 f  [b,h,s,64]
  float* VT   = ws + 33554432ull;          // 4194304 f   [b,h,s,8]
  unsigned* H1s = (unsigned*)(ws + 37748736ull);  // 2048*4096 u32 (hi|lo f16)
  unsigned* HVs = H1s;                     // 8192*512 u32, alias (after MLP)

  dim3 blk(256);
  // MLP in 4 chunks of 2048 token-rows to bound workspace
  for (int c = 0; c < 4; ++c) {
    const float* xc = x + (size_t)c * 2048 * 512;
    // H1s = split(relu(xc @ W1^T + b1))     M=2048 N=4096 K=512
    gemm_mfma<0, 0><<<dim3(32, 16), blk, 0, stream>>>(xc, W1, b1, H1s, 2048, 4096, 512, 0);
    // BLKT rows = H1 @ W2^T + b2            M=2048 N=4096 K=4096
    gemm_mfma<1, 2><<<dim3(32, 16), blk, 0, stream>>>(H1s, W2, b2, BLKT, 2048, 4096, 4096, c * 2048);
  }
  // normalize 8x8 blocks in place
  norm_kernel<<<131072, 256, 0, stream>>>(BLKT);
  // HVs = split(relu(x @ V1^T + c1))        M=8192 N=512 K=512
  gemm_mfma<0, 0><<<dim3(4, 64), blk, 0, stream>>>(x, V1, c1, HVs, 8192, 512, 512, 0);
  // VT = HV @ V2^T + c2 (scan layout)       M=8192 N=512 K=512
  gemm_mfma<1, 3><<<dim3(4, 64), blk, 0, stream>>>(HVs, V2, c2, VT, 8192, 512, 512, 0);
  // sequential affine scan -> out
  scan_kernel<<<256, 64, 0, stream>>>(BLKT, VT, a0, out);
}

// Round 5
// 1309.927 us; speedup vs baseline: 3.2670x; 1.1448x over previous
//
#include <hip/hip_runtime.h>
#include <hip/hip_bf16.h>
#include <cstddef>

// Problem constants: BS=4, SEQ=2048, EMB=512, BD=8, H=64; tokens M=8192.

typedef _Float16 f16;
typedef _Float16 f16x4 __attribute__((ext_vector_type(4)));
typedef _Float16 f16x8 __attribute__((ext_vector_type(8)));
typedef float f32x4 __attribute__((ext_vector_type(4)));

#define LDP 40  // padded LDS stride in f16 (80 B = 5*16B: 16B-aligned, ~2-way banks)

// ---------------------------------------------------------------------------
// Split-f16 MFMA GEMM:  C = op(A @ B^T + bias)
//   A: (M,K), B: (N,K) row-major.  Internally A,B split to f16 hi+lo;
//   product via 3x mfma_f32_16x16x32_f16 (hi*hi + hi*lo + lo*hi), fp32 acc.
// AFMT 0: A is fp32 (convert during staging)
// AFMT 1: A is packed u32 per element: low16 = hi f16 bits, high16 = lo f16
// MODE 0: relu, split, store packed u32 [M][N] (feeds AFMT=1 consumer)
// MODE 2: fp32 store to BLKT scan layout [b,h,s,64] (token row = roff+row)
// MODE 3: fp32 store to VT scan layout [b,h,s,8]
// Tile 128x128, BK=32, 256 threads = 4 waves, each wave 64x64 output.
// ---------------------------------------------------------------------------
__device__ inline void stage_f32(const float* __restrict__ src, int ldk, int k0,
                                 f16* shi, f16* slo, int tid) {
  const int row = tid >> 1, kb = (tid & 1) << 4;
  const float* p = src + (size_t)row * ldk + k0 + kb;
#pragma unroll
  for (int q = 0; q < 4; ++q) {
    float4 v = *(const float4*)(p + q * 4);
    f16x4 h, l;
    h.x = (f16)v.x; l.x = (f16)(v.x - (float)h.x);
    h.y = (f16)v.y; l.y = (f16)(v.y - (float)h.y);
    h.z = (f16)v.z; l.z = (f16)(v.z - (float)h.z);
    h.w = (f16)v.w; l.w = (f16)(v.w - (float)h.w);
    *(f16x4*)&shi[row * LDP + kb + q * 4] = h;
    *(f16x4*)&slo[row * LDP + kb + q * 4] = l;
  }
}

__device__ inline void stage_pk(const unsigned int* __restrict__ src, int ldk, int k0,
                                f16* shi, f16* slo, int tid) {
  const int row = tid >> 1, kb = (tid & 1) << 4;
  const unsigned int* p = src + (size_t)row * ldk + k0 + kb;
#pragma unroll
  for (int q = 0; q < 4; ++q) {
    uint4 v = *(const uint4*)(p + q * 4);
    ushort4 hu, lu;
    hu.x = (unsigned short)(v.x & 0xffff); lu.x = (unsigned short)(v.x >> 16);
    hu.y = (unsigned short)(v.y & 0xffff); lu.y = (unsigned short)(v.y >> 16);
    hu.z = (unsigned short)(v.z & 0xffff); lu.z = (unsigned short)(v.z >> 16);
    hu.w = (unsigned short)(v.w & 0xffff); lu.w = (unsigned short)(v.w >> 16);
    *(ushort4*)&shi[row * LDP + kb + q * 4] = hu;
    *(ushort4*)&slo[row * LDP + kb + q * 4] = lu;
  }
}

template<int AFMT, int MODE>
__global__ __launch_bounds__(256)
void gemm_mfma(const void* __restrict__ Av, const float* __restrict__ B,
               const float* __restrict__ bias, void* __restrict__ Ov,
               int M, int N, int K, int roff) {
  __shared__ f16 sAhi[128 * LDP];
  __shared__ f16 sAlo[128 * LDP];
  __shared__ f16 sBhi[128 * LDP];
  __shared__ f16 sBlo[128 * LDP];
  const int tid = threadIdx.x;
  const int m0 = blockIdx.y << 7, n0 = blockIdx.x << 7;
  const int lane = tid & 63, wid = tid >> 6;
  const int wr = wid >> 1, wc = wid & 1;

  f32x4 acc[4][4];
#pragma unroll
  for (int m = 0; m < 4; ++m)
#pragma unroll
    for (int n = 0; n < 4; ++n) acc[m][n] = (f32x4)0.f;

  const int fr = lane & 15, fk = (lane >> 4) << 3;

  for (int k0 = 0; k0 < K; k0 += 32) {
    __syncthreads();
    if (AFMT == 0)
      stage_f32((const float*)Av + (size_t)m0 * K, K, k0, sAhi, sAlo, tid);
    else
      stage_pk((const unsigned int*)Av + (size_t)m0 * K, K, k0, sAhi, sAlo, tid);
    stage_f32(B + (size_t)n0 * K, K, k0, sBhi, sBlo, tid);
    __syncthreads();

    f16x8 ah[4], al[4], bh[4], bl[4];
#pragma unroll
    for (int m = 0; m < 4; ++m) {
      const int r = wr * 64 + m * 16 + fr;
      ah[m] = *(const f16x8*)&sAhi[r * LDP + fk];
      al[m] = *(const f16x8*)&sAlo[r * LDP + fk];
    }
#pragma unroll
    for (int n = 0; n < 4; ++n) {
      const int r = wc * 64 + n * 16 + fr;
      bh[n] = *(const f16x8*)&sBhi[r * LDP + fk];
      bl[n] = *(const f16x8*)&sBlo[r * LDP + fk];
    }
#pragma unroll
    for (int m = 0; m < 4; ++m)
#pragma unroll
      for (int n = 0; n < 4; ++n) {
        acc[m][n] = __builtin_amdgcn_mfma_f32_16x16x32_f16(ah[m], bh[n], acc[m][n], 0, 0, 0);
        acc[m][n] = __builtin_amdgcn_mfma_f32_16x16x32_f16(ah[m], bl[n], acc[m][n], 0, 0, 0);
        acc[m][n] = __builtin_amdgcn_mfma_f32_16x16x32_f16(al[m], bh[n], acc[m][n], 0, 0, 0);
      }
  }

  // Epilogue. D frag (m,n): col = n0+wc*64+n*16+(lane&15),
  //                         row = m0+wr*64+m*16+(lane>>4)*4+r
  const int fq = lane >> 4;
  float bz[4];
#pragma unroll
  for (int n = 0; n < 4; ++n) bz[n] = bias[n0 + wc * 64 + n * 16 + fr];

#pragma unroll
  for (int m = 0; m < 4; ++m)
#pragma unroll
    for (int n = 0; n < 4; ++n) {
      const int col = n0 + wc * 64 + n * 16 + fr;
#pragma unroll
      for (int r = 0; r < 4; ++r) {
        const int row = m0 + wr * 64 + m * 16 + fq * 4 + r;
        float v = acc[m][n][r] + bz[n];
        if (MODE == 0) {
          v = fmaxf(v, 0.f);
          f16 h = (f16)v;
          f16 l = (f16)(v - (float)h);
          unsigned pk = ((unsigned)__builtin_bit_cast(unsigned short, l) << 16)
                      | (unsigned)__builtin_bit_cast(unsigned short, h);
          ((unsigned*)Ov)[(size_t)row * N + col] = pk;
        } else {
          const int grow = roff + row;
          const int bb = grow >> 11, s = grow & 2047;  // SEQ=2048
          if (MODE == 2) {
            ((float*)Ov)[(((size_t)(bb * 64 + (col >> 6)) * 2048 + s) << 6) + (col & 63)] = v;
          } else {
            ((float*)Ov)[(((size_t)(bb * 64 + (col >> 3)) * 2048 + s) << 3) + (col & 7)] = v;
          }
        }
      }
    }
}

// ---------------------------------------------------------------------------
// Block normalization in place on BLKT ([b,h,s,64]); one wave per (b,h,s).
// lane = i*8+j. x -= mean_i; norm_j = (sum_i |x|^1.2)^(1/1.2); x /= max_j norm_j.
// ---------------------------------------------------------------------------
__global__ __launch_bounds__(256)
void norm_kernel(float* __restrict__ BLKT) {
  const int task = (blockIdx.x << 2) + (threadIdx.x >> 6);
  const int lane = threadIdx.x & 63;
  float* p = BLKT + (size_t)task * 64;
  float x = p[lane];
  float m = x;
  m += __shfl_xor(m, 8);
  m += __shfl_xor(m, 16);
  m += __shfl_xor(m, 32);
  x -= m * 0.125f;
  float ax = fabsf(x);
  float t = exp2f(1.2f * log2f(ax));  // |x|^1.2 ; log2f(0)=-inf -> exp2f=0, OK
  t += __shfl_xor(t, 8);
  t += __shfl_xor(t, 16);
  t += __shfl_xor(t, 32);
  float nrm = exp2f((1.0f / 1.2f) * log2f(t));
  float mx = nrm;
  mx = fmaxf(mx, __shfl_xor(mx, 1));
  mx = fmaxf(mx, __shfl_xor(mx, 2));
  mx = fmaxf(mx, __shfl_xor(mx, 4));
  p[lane] = x / mx;
}

// ---------------------------------------------------------------------------
// Chunked affine scan, 3 phases. Recurrence per stream (b,h):
//   y_{s+1} = A_s y_s + v_s ; out[s] = y_{s+1}, y_0 = a0[h].
// T=16 segments of L=128 steps. S1: per-segment affine summary [M_t|c_t];
// S2: 16-step scan over summaries -> boundary states; S3: re-apply within
// segments from boundary states. 4096 waves in S1/S3 (16/CU) hide DS latency.
// ---------------------------------------------------------------------------
#define SCH2 16
#define SEGL 128
#define NSEG 16

__global__ __launch_bounds__(256)
void scan_part1(const float* __restrict__ BLKT, const float* __restrict__ VT,
                float* __restrict__ Msum, float* __restrict__ Csum) {
  __shared__ __align__(16) float Abuf[4][2][SCH2 * 64];
  __shared__ __align__(16) float vbuf[4][2][SCH2 * 8];
  const int w = threadIdx.x >> 6, lane = threadIdx.x & 63;
  const int id = blockIdx.x * 4 + w;       // stream*NSEG + t
  const int stream = id >> 4, t = id & 15;
  const int i = lane >> 3, j = lane & 7;
  const float* Ab = BLKT + (size_t)stream * (2048 * 64) + (size_t)t * (SEGL * 64);
  const float* Vb = VT + (size_t)stream * (2048 * 8) + (size_t)t * (SEGL * 8);

  float m = (i == j) ? 1.f : 0.f;  // M = I (lane holds M[i][j])
  float cj = 0.f;                  // c = 0 (lane holds c[j])

  float4 ra[4]; float2 rv;
  auto loadc = [&](int c) {
    const float* sA = Ab + c * (SCH2 * 64);
#pragma unroll
    for (int q = 0; q < 4; ++q) ra[q] = *(const float4*)(sA + q * 256 + lane * 4);
    rv = *(const float2*)(Vb + c * (SCH2 * 8) + lane * 2);
  };
  auto store_lds = [&](int slot) {
#pragma unroll
    for (int q = 0; q < 4; ++q)
      *(float4*)&Abuf[w][slot][q * 256 + lane * 4] = ra[q];
    *(float2*)&vbuf[w][slot][lane * 2] = rv;
  };

  loadc(0); store_lds(0);
  int cur = 0;
  const int NC = SEGL / SCH2;  // 8
  for (int c = 0; c < NC; ++c) {
    if (c + 1 < NC) loadc(c + 1);
#pragma unroll
    for (int s = 0; s < SCH2; ++s) {
      const float aij = Abuf[w][cur][s * 64 + lane];  // A[i][j]
      // c <- A c + v
      float p = aij * cj;
      p += __shfl_xor(p, 1);
      p += __shfl_xor(p, 2);
      p += __shfl_xor(p, 4);
      const float cn = p + vbuf[w][cur][s * 8 + i];   // c_new[i] on group i
      cj = __shfl(cn, j << 3);                        // redistribute c[j]
      // M <- A M : m_new[i][j] = sum_k A[i][k] * M[k][j]
      float arow[8];
      *(float4*)&arow[0] = *(const float4*)&Abuf[w][cur][s * 64 + i * 8];
      *(float4*)&arow[4] = *(const float4*)&Abuf[w][cur][s * 64 + i * 8 + 4];
      float mn = 0.f;
#pragma unroll
      for (int k = 0; k < 8; ++k)
        mn = fmaf(arow[k], __shfl(m, (k << 3) | j), mn);
      m = mn;
    }
    if (c + 1 < NC) store_lds(cur ^ 1);
    cur ^= 1;
  }
  Msum[(size_t)id * 64 + lane] = m;
  if (lane < 8) Csum[(size_t)id * 8 + lane] = cj;
}

__global__ __launch_bounds__(64)
void scan_part2(const float* __restrict__ Msum, const float* __restrict__ Csum,
                const float* __restrict__ a0, float* __restrict__ Ybnd) {
  const int stream = blockIdx.x;  // b*64 + h
  const int lane = threadIdx.x;
  const int i = lane >> 3, j = lane & 7;
  const int h = stream & 63;
  float y = a0[h * 8 + j];
  for (int t = 0; t < NSEG; ++t) {
    const size_t sid = (size_t)stream * NSEG + t;
    if (lane < 8) Ybnd[sid * 8 + lane] = y;  // state at segment start
    float p = Msum[sid * 64 + lane] * y;
    p += __shfl_xor(p, 1);
    p += __shfl_xor(p, 2);
    p += __shfl_xor(p, 4);
    const float yn = p + Csum[sid * 8 + i];
    y = __shfl(yn, j << 3);
  }
}

__global__ __launch_bounds__(256)
void scan_part3(const float* __restrict__ BLKT, const float* __restrict__ VT,
                const float* __restrict__ Ybnd, float* __restrict__ out) {
  __shared__ __align__(16) float Abuf[4][2][SCH2 * 64];
  __shared__ __align__(16) float vbuf[4][2][SCH2 * 8];
  const int w = threadIdx.x >> 6, lane = threadIdx.x & 63;
  const int id = blockIdx.x * 4 + w;
  const int stream = id >> 4, t = id & 15;
  const int b = stream >> 6, h = stream & 63;
  const int i = lane >> 3, j = lane & 7;
  const float* Ab = BLKT + (size_t)stream * (2048 * 64) + (size_t)t * (SEGL * 64);
  const float* Vb = VT + (size_t)stream * (2048 * 8) + (size_t)t * (SEGL * 8);
  float* ob = out + (size_t)b * (2048 * 512) + (size_t)(t * SEGL) * 512 + h * 8;

  float y = Ybnd[(size_t)id * 8 + j];

  float4 ra[4]; float2 rv;
  auto loadc = [&](int c) {
    const float* sA = Ab + c * (SCH2 * 64);
#pragma unroll
    for (int q = 0; q < 4; ++q) ra[q] = *(const float4*)(sA + q * 256 + lane * 4);
    rv = *(const float2*)(Vb + c * (SCH2 * 8) + lane * 2);
  };
  auto store_lds = [&](int slot) {
#pragma unroll
    for (int q = 0; q < 4; ++q)
      *(float4*)&Abuf[w][slot][q * 256 + lane * 4] = ra[q];
    *(float2*)&vbuf[w][slot][lane * 2] = rv;
  };

  loadc(0); store_lds(0);
  int cur = 0;
  const int NC = SEGL / SCH2;
  for (int c = 0; c < NC; ++c) {
    if (c + 1 < NC) loadc(c + 1);
#pragma unroll
    for (int s = 0; s < SCH2; ++s) {
      const float aij = Abuf[w][cur][s * 64 + lane];
      float p = aij * y;
      p += __shfl_xor(p, 1);
      p += __shfl_xor(p, 2);
      p += __shfl_xor(p, 4);
      const float yn = p + vbuf[w][cur][s * 8 + i];
      if (j == 0) ob[(size_t)(c * SCH2 + s) * 512 + i] = yn;
      y = __shfl(yn, j << 3);
    }
    if (c + 1 < NC) store_lds(cur ^ 1);
    cur ^= 1;
  }
}

// ---------------------------------------------------------------------------
extern "C" void kernel_launch(void* const* d_in, const int* in_sizes, int n_in,
                              void* d_out, int out_size, void* d_ws, size_t ws_size,
                              hipStream_t stream) {
  const float* x  = (const float*)d_in[0];
  const float* W1 = (const float*)d_in[1];
  const float* b1 = (const float*)d_in[2];
  const float* W2 = (const float*)d_in[3];
  const float* b2 = (const float*)d_in[4];
  const float* V1 = (const float*)d_in[5];
  const float* c1 = (const float*)d_in[6];
  const float* V2 = (const float*)d_in[7];
  const float* c2 = (const float*)d_in[8];
  const float* a0 = (const float*)d_in[9];
  float* out = (float*)d_out;
  float* ws = (float*)d_ws;

  // Workspace (floats), total 46,465,024 floats = 185.9 MB:
  float* BLKT = ws;                        // 33554432 f  [b,h,s,64]
  float* VT   = ws + 33554432ull;          // 4194304 f   [b,h,s,8]
  unsigned* H1s = (unsigned*)(ws + 37748736ull);  // 2048*4096 u32 (hi|lo f16)
  unsigned* HVs = H1s;                     // 8192*512 u32, alias (after MLP)
  float* Msum = ws + 46137344ull;          // 256*16*64
  float* Csum = ws + 46399488ull;          // 256*16*8
  float* Ybnd = ws + 46432256ull;          // 256*16*8

  dim3 blk(256);
  // MLP in 4 chunks of 2048 token-rows to bound workspace
  for (int c = 0; c < 4; ++c) {
    const float* xc = x + (size_t)c * 2048 * 512;
    // H1s = split(relu(xc @ W1^T + b1))     M=2048 N=4096 K=512
    gemm_mfma<0, 0><<<dim3(32, 16), blk, 0, stream>>>(xc, W1, b1, H1s, 2048, 4096, 512, 0);
    // BLKT rows = H1 @ W2^T + b2            M=2048 N=4096 K=4096
    gemm_mfma<1, 2><<<dim3(32, 16), blk, 0, stream>>>(H1s, W2, b2, BLKT, 2048, 4096, 4096, c * 2048);
  }
  // normalize 8x8 blocks in place
  norm_kernel<<<131072, 256, 0, stream>>>(BLKT);
  // HVs = split(relu(x @ V1^T + c1))        M=8192 N=512 K=512
  gemm_mfma<0, 0><<<dim3(4, 64), blk, 0, stream>>>(x, V1, c1, HVs, 8192, 512, 512, 0);
  // VT = HV @ V2^T + c2 (scan layout)       M=8192 N=512 K=512
  gemm_mfma<1, 3><<<dim3(4, 64), blk, 0, stream>>>(HVs, V2, c2, VT, 8192, 512, 512, 0);
  // chunked scan -> out
  scan_part1<<<1024, 256, 0, stream>>>(BLKT, VT, Msum, Csum);
  scan_part2<<<256, 64, 0, stream>>>(Msum, Csum, a0, Ybnd);
  scan_part3<<<1024, 256, 0, stream>>>(BLKT, VT, Ybnd, out);
}

// Round 6
// 1040.126 us; speedup vs baseline: 4.1145x; 1.2594x over previous
//
#include <hip/hip_runtime.h>
#include <hip/hip_bf16.h>
#include <cstddef>

// Problem constants: BS=4, SEQ=2048, EMB=512, BD=8, H=64; tokens M=8192.

typedef _Float16 f16;
typedef _Float16 f16x4 __attribute__((ext_vector_type(4)));
typedef _Float16 f16x8 __attribute__((ext_vector_type(8)));
typedef float f32x4 __attribute__((ext_vector_type(4)));

#define LDP 40  // padded LDS stride in f16 for the legacy (VALU-staged) GEMM

// ---------------------------------------------------------------------------
// One-shot fp32 -> (hi,lo) f16 plane split.  v = hi + lo, |lo| <= ulp(hi)/2.
// ---------------------------------------------------------------------------
__global__ __launch_bounds__(256)
void split_kernel(const float* __restrict__ in, f16* __restrict__ hi,
                  f16* __restrict__ lo, int n) {
  const int idx = (blockIdx.x * 256 + threadIdx.x) * 4;
  if (idx >= n) return;
  float4 v = *(const float4*)(in + idx);
  f16x4 h, l;
  h.x = (f16)v.x; l.x = (f16)(v.x - (float)h.x);
  h.y = (f16)v.y; l.y = (f16)(v.y - (float)h.y);
  h.z = (f16)v.z; l.z = (f16)(v.z - (float)h.z);
  h.w = (f16)v.w; l.w = (f16)(v.w - (float)h.w);
  *(f16x4*)(hi + idx) = h;
  *(f16x4*)(lo + idx) = l;
}

// ---------------------------------------------------------------------------
// Legacy split-f16 MFMA GEMM (VALU staging):  C = op(A @ B^T + bias)
// AFMT 0: A fp32; AFMT 1: A packed u32 (hi|lo f16)
// MODE 0: relu -> packed u32 out     MODE 2: fp32 -> BLKT scan layout
// MODE 3: fp32 -> VT scan layout     MODE 4: relu -> hi/lo f16 planes out
// ---------------------------------------------------------------------------
__device__ inline void stage_f32(const float* __restrict__ src, int ldk, int k0,
                                 f16* shi, f16* slo, int tid) {
  const int row = tid >> 1, kb = (tid & 1) << 4;
  const float* p = src + (size_t)row * ldk + k0 + kb;
#pragma unroll
  for (int q = 0; q < 4; ++q) {
    float4 v = *(const float4*)(p + q * 4);
    f16x4 h, l;
    h.x = (f16)v.x; l.x = (f16)(v.x - (float)h.x);
    h.y = (f16)v.y; l.y = (f16)(v.y - (float)h.y);
    h.z = (f16)v.z; l.z = (f16)(v.z - (float)h.z);
    h.w = (f16)v.w; l.w = (f16)(v.w - (float)h.w);
    *(f16x4*)&shi[row * LDP + kb + q * 4] = h;
    *(f16x4*)&slo[row * LDP + kb + q * 4] = l;
  }
}

__device__ inline void stage_pk(const unsigned int* __restrict__ src, int ldk, int k0,
                                f16* shi, f16* slo, int tid) {
  const int row = tid >> 1, kb = (tid & 1) << 4;
  const unsigned int* p = src + (size_t)row * ldk + k0 + kb;
#pragma unroll
  for (int q = 0; q < 4; ++q) {
    uint4 v = *(const uint4*)(p + q * 4);
    ushort4 hu, lu;
    hu.x = (unsigned short)(v.x & 0xffff); lu.x = (unsigned short)(v.x >> 16);
    hu.y = (unsigned short)(v.y & 0xffff); lu.y = (unsigned short)(v.y >> 16);
    hu.z = (unsigned short)(v.z & 0xffff); lu.z = (unsigned short)(v.z >> 16);
    hu.w = (unsigned short)(v.w & 0xffff); lu.w = (unsigned short)(v.w >> 16);
    *(ushort4*)&shi[row * LDP + kb + q * 4] = hu;
    *(ushort4*)&slo[row * LDP + kb + q * 4] = lu;
  }
}

template<int AFMT, int MODE>
__global__ __launch_bounds__(256)
void gemm_mfma(const void* __restrict__ Av, const float* __restrict__ B,
               const float* __restrict__ bias, void* __restrict__ Ov,
               int M, int N, int K, int roff) {
  __shared__ f16 sAhi[128 * LDP];
  __shared__ f16 sAlo[128 * LDP];
  __shared__ f16 sBhi[128 * LDP];
  __shared__ f16 sBlo[128 * LDP];
  const int tid = threadIdx.x;
  const int m0 = blockIdx.y << 7, n0 = blockIdx.x << 7;
  const int lane = tid & 63, wid = tid >> 6;
  const int wr = wid >> 1, wc = wid & 1;

  f32x4 acc[4][4];
#pragma unroll
  for (int m = 0; m < 4; ++m)
#pragma unroll
    for (int n = 0; n < 4; ++n) acc[m][n] = (f32x4)0.f;

  const int fr = lane & 15, fk = (lane >> 4) << 3;

  for (int k0 = 0; k0 < K; k0 += 32) {
    __syncthreads();
    if (AFMT == 0)
      stage_f32((const float*)Av + (size_t)m0 * K, K, k0, sAhi, sAlo, tid);
    else
      stage_pk((const unsigned int*)Av + (size_t)m0 * K, K, k0, sAhi, sAlo, tid);
    stage_f32(B + (size_t)n0 * K, K, k0, sBhi, sBlo, tid);
    __syncthreads();

    f16x8 ah[4], al[4], bh[4], bl[4];
#pragma unroll
    for (int m = 0; m < 4; ++m) {
      const int r = wr * 64 + m * 16 + fr;
      ah[m] = *(const f16x8*)&sAhi[r * LDP + fk];
      al[m] = *(const f16x8*)&sAlo[r * LDP + fk];
    }
#pragma unroll
    for (int n = 0; n < 4; ++n) {
      const int r = wc * 64 + n * 16 + fr;
      bh[n] = *(const f16x8*)&sBhi[r * LDP + fk];
      bl[n] = *(const f16x8*)&sBlo[r * LDP + fk];
    }
#pragma unroll
    for (int m = 0; m < 4; ++m)
#pragma unroll
      for (int n = 0; n < 4; ++n) {
        acc[m][n] = __builtin_amdgcn_mfma_f32_16x16x32_f16(ah[m], bh[n], acc[m][n], 0, 0, 0);
        acc[m][n] = __builtin_amdgcn_mfma_f32_16x16x32_f16(ah[m], bl[n], acc[m][n], 0, 0, 0);
        acc[m][n] = __builtin_amdgcn_mfma_f32_16x16x32_f16(al[m], bh[n], acc[m][n], 0, 0, 0);
      }
  }

  const int fq = lane >> 4;
  float bz[4];
#pragma unroll
  for (int n = 0; n < 4; ++n) bz[n] = bias[n0 + wc * 64 + n * 16 + fr];

#pragma unroll
  for (int m = 0; m < 4; ++m)
#pragma unroll
    for (int n = 0; n < 4; ++n) {
      const int col = n0 + wc * 64 + n * 16 + fr;
#pragma unroll
      for (int r = 0; r < 4; ++r) {
        const int row = m0 + wr * 64 + m * 16 + fq * 4 + r;
        float v = acc[m][n][r] + bz[n];
        if (MODE == 0 || MODE == 4) {
          v = fmaxf(v, 0.f);
          f16 h = (f16)v;
          f16 l = (f16)(v - (float)h);
          if (MODE == 0) {
            unsigned pk = ((unsigned)__builtin_bit_cast(unsigned short, l) << 16)
                        | (unsigned)__builtin_bit_cast(unsigned short, h);
            ((unsigned*)Ov)[(size_t)row * N + col] = pk;
          } else {
            f16* Hhi = (f16*)Ov;
            f16* Hlo = Hhi + (size_t)M * N;
            Hhi[(size_t)row * N + col] = h;
            Hlo[(size_t)row * N + col] = l;
          }
        } else {
          const int grow = roff + row;
          const int bb = grow >> 11, s = grow & 2047;  // SEQ=2048
          if (MODE == 2) {
            ((float*)Ov)[(((size_t)(bb * 64 + (col >> 6)) * 2048 + s) << 6) + (col & 63)] = v;
          } else {
            ((float*)Ov)[(((size_t)(bb * 64 + (col >> 3)) * 2048 + s) << 3) + (col & 7)] = v;
          }
        }
      }
    }
}

// ---------------------------------------------------------------------------
// DMA-staged split-f16 GEMM2 with fused block-norm, writes BLKT scan layout.
// A,B given as separate hi/lo f16 planes (row-major, leading dim K).
// Tile 128x128, BK=64, 4 waves; each wave DMA-stages one plane (16x
// global_load_lds of 16B).  LDS linear with rotate swizzle: stored 16B chunk
// c of row r holds source chunk (c - r) & 7; reads use c = (want + r) & 7
// -> ds_read_b128 2-way conflict (free).  Epilogue: bias + blk-norm fused:
//   x -= mean_i; nrm_j = (sum_i|x|^1.2)^(1/1.2); x /= max_j nrm_j.
// Wave holds 64 rows x 64 cols = one full head per row -> in-register norm.
// ---------------------------------------------------------------------------
__global__ __launch_bounds__(256)
void gemm2_dma(const f16* __restrict__ Ahi, const f16* __restrict__ Alo,
               const f16* __restrict__ Bhi, const f16* __restrict__ Blo,
               const float* __restrict__ bias, float* __restrict__ O,
               int M, int N, int K, int roff) {
  __shared__ f16 sA[2][128 * 64];
  __shared__ f16 sB[2][128 * 64];
  const int tid = threadIdx.x, lane = tid & 63, wid = tid >> 6;
  const int m0 = blockIdx.y << 7, n0 = blockIdx.x << 7;
  const int wr = wid >> 1, wc = wid & 1;
  const int fr = lane & 15, g = lane >> 4;

  f32x4 acc[4][4];
#pragma unroll
  for (int m = 0; m < 4; ++m)
#pragma unroll
    for (int n = 0; n < 4; ++n) acc[m][n] = (f32x4)0.f;

  // staging: wave 0 -> A hi, 1 -> A lo, 2 -> B hi, 3 -> B lo
  const f16* gsrc = (wid == 0) ? Ahi + (size_t)m0 * K
                  : (wid == 1) ? Alo + (size_t)m0 * K
                  : (wid == 2) ? Bhi + (size_t)n0 * K
                               : Blo + (size_t)n0 * K;
  f16* ldst = (wid == 0) ? sA[0] : (wid == 1) ? sA[1]
            : (wid == 2) ? sB[0] : sB[1];
  const int lrow = lane >> 3;  // 0..7 within an issue
  const int lc = lane & 7;     // stored chunk

  for (int k0 = 0; k0 < K; k0 += 64) {
    __syncthreads();  // previous iteration's reads complete
#pragma unroll
    for (int i = 0; i < 16; ++i) {
      const int r = i * 8 + lrow;        // tile row 0..127
      const int sg = (lc - r) & 7;       // source chunk for stored slot lc
      const f16* sp = gsrc + (size_t)r * K + k0 + sg * 8;
      __builtin_amdgcn_global_load_lds(
          (const __attribute__((address_space(1))) unsigned int*)sp,
          (__attribute__((address_space(3))) unsigned int*)(ldst + i * 512),
          16, 0, 0);
    }
    __syncthreads();  // compiler drains vmcnt before barrier -> tile ready

#pragma unroll
    for (int kk = 0; kk < 2; ++kk) {
      f16x8 ah[4], al[4], bh[4], bl[4];
#pragma unroll
      for (int m = 0; m < 4; ++m) {
        const int r = wr * 64 + m * 16 + fr;
        const int off = r * 64 + ((((kk << 2) + g) + r) & 7) * 8;
        ah[m] = *(const f16x8*)&sA[0][off];
        al[m] = *(const f16x8*)&sA[1][off];
      }
#pragma unroll
      for (int n = 0; n < 4; ++n) {
        const int r = wc * 64 + n * 16 + fr;
        const int off = r * 64 + ((((kk << 2) + g) + r) & 7) * 8;
        bh[n] = *(const f16x8*)&sB[0][off];
        bl[n] = *(const f16x8*)&sB[1][off];
      }
#pragma unroll
      for (int m = 0; m < 4; ++m)
#pragma unroll
        for (int n = 0; n < 4; ++n) {
          acc[m][n] = __builtin_amdgcn_mfma_f32_16x16x32_f16(ah[m], bh[n], acc[m][n], 0, 0, 0);
          acc[m][n] = __builtin_amdgcn_mfma_f32_16x16x32_f16(ah[m], bl[n], acc[m][n], 0, 0, 0);
          acc[m][n] = __builtin_amdgcn_mfma_f32_16x16x32_f16(al[m], bh[n], acc[m][n], 0, 0, 0);
        }
    }
  }

  // Epilogue: bias + fused block-norm + scan-layout store.
  // Row of a fragment: m0+wr*64+m*16+fq*4+r;  col: n0+wc*64+n*16+fr.
  // Within-head col = n*16+fr: i = 2n+(fr>>3), j = fr&7.
  const int fq = lane >> 4;
  float bz[4];
#pragma unroll
  for (int n = 0; n < 4; ++n) bz[n] = bias[n0 + wc * 64 + n * 16 + fr];

#pragma unroll
  for (int m = 0; m < 4; ++m) {
#pragma unroll
    for (int r = 0; r < 4; ++r) {
      float v[4];
#pragma unroll
      for (int n = 0; n < 4; ++n) v[n] = acc[m][n][r] + bz[n];
      float s = v[0] + v[1] + v[2] + v[3];
      s += __shfl_xor(s, 8);
      const float mean = s * 0.125f;
      float t = 0.f;
#pragma unroll
      for (int n = 0; n < 4; ++n) {
        v[n] -= mean;
        t += exp2f(1.2f * log2f(fabsf(v[n])));  // |x|^1.2 (0 -> 0)
      }
      t += __shfl_xor(t, 8);                    // sum over i: nrm_j^1.2
      float nrm = exp2f((1.0f / 1.2f) * log2f(t));
      nrm = fmaxf(nrm, __shfl_xor(nrm, 1));
      nrm = fmaxf(nrm, __shfl_xor(nrm, 2));
      nrm = fmaxf(nrm, __shfl_xor(nrm, 4));     // max over j
      const float inv = 1.f / nrm;
      const int row = m0 + wr * 64 + m * 16 + fq * 4 + r;
      const int grow = roff + row;
      const int bb = grow >> 11, ss = grow & 2047;
#pragma unroll
      for (int n = 0; n < 4; ++n) {
        const int col = n0 + wc * 64 + n * 16 + fr;
        O[(((size_t)(bb * 64 + (col >> 6)) * 2048 + ss) << 6) + (col & 63)] = v[n] * inv;
      }
    }
  }
}

// ---------------------------------------------------------------------------
// Block normalization in place on BLKT (layout B fallback only).
// ---------------------------------------------------------------------------
__global__ __launch_bounds__(256)
void norm_kernel(float* __restrict__ BLKT) {
  const int task = (blockIdx.x << 2) + (threadIdx.x >> 6);
  const int lane = threadIdx.x & 63;
  float* p = BLKT + (size_t)task * 64;
  float x = p[lane];
  float m = x;
  m += __shfl_xor(m, 8);
  m += __shfl_xor(m, 16);
  m += __shfl_xor(m, 32);
  x -= m * 0.125f;
  float ax = fabsf(x);
  float t = exp2f(1.2f * log2f(ax));
  t += __shfl_xor(t, 8);
  t += __shfl_xor(t, 16);
  t += __shfl_xor(t, 32);
  float nrm = exp2f((1.0f / 1.2f) * log2f(t));
  float mx = nrm;
  mx = fmaxf(mx, __shfl_xor(mx, 1));
  mx = fmaxf(mx, __shfl_xor(mx, 2));
  mx = fmaxf(mx, __shfl_xor(mx, 4));
  p[lane] = x / mx;
}

// ---------------------------------------------------------------------------
// Chunked affine scan (3 phases), unchanged from R5.
// ---------------------------------------------------------------------------
#define SCH2 16
#define SEGL 128
#define NSEG 16

__global__ __launch_bounds__(256)
void scan_part1(const float* __restrict__ BLKT, const float* __restrict__ VT,
                float* __restrict__ Msum, float* __restrict__ Csum) {
  __shared__ __align__(16) float Abuf[4][2][SCH2 * 64];
  __shared__ __align__(16) float vbuf[4][2][SCH2 * 8];
  const int w = threadIdx.x >> 6, lane = threadIdx.x & 63;
  const int id = blockIdx.x * 4 + w;
  const int stream = id >> 4, t = id & 15;
  const int i = lane >> 3, j = lane & 7;
  const float* Ab = BLKT + (size_t)stream * (2048 * 64) + (size_t)t * (SEGL * 64);
  const float* Vb = VT + (size_t)stream * (2048 * 8) + (size_t)t * (SEGL * 8);

  float m = (i == j) ? 1.f : 0.f;
  float cj = 0.f;

  float4 ra[4]; float2 rv;
  auto loadc = [&](int c) {
    const float* sA = Ab + c * (SCH2 * 64);
#pragma unroll
    for (int q = 0; q < 4; ++q) ra[q] = *(const float4*)(sA + q * 256 + lane * 4);
    rv = *(const float2*)(Vb + c * (SCH2 * 8) + lane * 2);
  };
  auto store_lds = [&](int slot) {
#pragma unroll
    for (int q = 0; q < 4; ++q)
      *(float4*)&Abuf[w][slot][q * 256 + lane * 4] = ra[q];
    *(float2*)&vbuf[w][slot][lane * 2] = rv;
  };

  loadc(0); store_lds(0);
  int cur = 0;
  const int NC = SEGL / SCH2;
  for (int c = 0; c < NC; ++c) {
    if (c + 1 < NC) loadc(c + 1);
#pragma unroll
    for (int s = 0; s < SCH2; ++s) {
      const float aij = Abuf[w][cur][s * 64 + lane];
      float p = aij * cj;
      p += __shfl_xor(p, 1);
      p += __shfl_xor(p, 2);
      p += __shfl_xor(p, 4);
      const float cn = p + vbuf[w][cur][s * 8 + i];
      cj = __shfl(cn, j << 3);
      float arow[8];
      *(float4*)&arow[0] = *(const float4*)&Abuf[w][cur][s * 64 + i * 8];
      *(float4*)&arow[4] = *(const float4*)&Abuf[w][cur][s * 64 + i * 8 + 4];
      float mn = 0.f;
#pragma unroll
      for (int k = 0; k < 8; ++k)
        mn = fmaf(arow[k], __shfl(m, (k << 3) | j), mn);
      m = mn;
    }
    if (c + 1 < NC) store_lds(cur ^ 1);
    cur ^= 1;
  }
  Msum[(size_t)id * 64 + lane] = m;
  if (lane < 8) Csum[(size_t)id * 8 + lane] = cj;
}

__global__ __launch_bounds__(64)
void scan_part2(const float* __restrict__ Msum, const float* __restrict__ Csum,
                const float* __restrict__ a0, float* __restrict__ Ybnd) {
  const int stream = blockIdx.x;
  const int lane = threadIdx.x;
  const int i = lane >> 3, j = lane & 7;
  const int h = stream & 63;
  float y = a0[h * 8 + j];
  for (int t = 0; t < NSEG; ++t) {
    const size_t sid = (size_t)stream * NSEG + t;
    if (lane < 8) Ybnd[sid * 8 + lane] = y;
    float p = Msum[sid * 64 + lane] * y;
    p += __shfl_xor(p, 1);
    p += __shfl_xor(p, 2);
    p += __shfl_xor(p, 4);
    const float yn = p + Csum[sid * 8 + i];
    y = __shfl(yn, j << 3);
  }
}

__global__ __launch_bounds__(256)
void scan_part3(const float* __restrict__ BLKT, const float* __restrict__ VT,
                const float* __restrict__ Ybnd, float* __restrict__ out) {
  __shared__ __align__(16) float Abuf[4][2][SCH2 * 64];
  __shared__ __align__(16) float vbuf[4][2][SCH2 * 8];
  const int w = threadIdx.x >> 6, lane = threadIdx.x & 63;
  const int id = blockIdx.x * 4 + w;
  const int stream = id >> 4, t = id & 15;
  const int b = stream >> 6, h = stream & 63;
  const int i = lane >> 3, j = lane & 7;
  const float* Ab = BLKT + (size_t)stream * (2048 * 64) + (size_t)t * (SEGL * 64);
  const float* Vb = VT + (size_t)stream * (2048 * 8) + (size_t)t * (SEGL * 8);
  float* ob = out + (size_t)b * (2048 * 512) + (size_t)(t * SEGL) * 512 + h * 8;

  float y = Ybnd[(size_t)id * 8 + j];

  float4 ra[4]; float2 rv;
  auto loadc = [&](int c) {
    const float* sA = Ab + c * (SCH2 * 64);
#pragma unroll
    for (int q = 0; q < 4; ++q) ra[q] = *(const float4*)(sA + q * 256 + lane * 4);
    rv = *(const float2*)(Vb + c * (SCH2 * 8) + lane * 2);
  };
  auto store_lds = [&](int slot) {
#pragma unroll
    for (int q = 0; q < 4; ++q)
      *(float4*)&Abuf[w][slot][q * 256 + lane * 4] = ra[q];
    *(float2*)&vbuf[w][slot][lane * 2] = rv;
  };

  loadc(0); store_lds(0);
  int cur = 0;
  const int NC = SEGL / SCH2;
  for (int c = 0; c < NC; ++c) {
    if (c + 1 < NC) loadc(c + 1);
#pragma unroll
    for (int s = 0; s < SCH2; ++s) {
      const float aij = Abuf[w][cur][s * 64 + lane];
      float p = aij * y;
      p += __shfl_xor(p, 1);
      p += __shfl_xor(p, 2);
      p += __shfl_xor(p, 4);
      const float yn = p + vbuf[w][cur][s * 8 + i];
      if (j == 0) ob[(size_t)(c * SCH2 + s) * 512 + i] = yn;
      y = __shfl(yn, j << 3);
    }
    if (c + 1 < NC) store_lds(cur ^ 1);
    cur ^= 1;
  }
}

// ---------------------------------------------------------------------------
extern "C" void kernel_launch(void* const* d_in, const int* in_sizes, int n_in,
                              void* d_out, int out_size, void* d_ws, size_t ws_size,
                              hipStream_t stream) {
  const float* x  = (const float*)d_in[0];
  const float* W1 = (const float*)d_in[1];
  const float* b1 = (const float*)d_in[2];
  const float* W2 = (const float*)d_in[3];
  const float* b2 = (const float*)d_in[4];
  const float* V1 = (const float*)d_in[5];
  const float* c1 = (const float*)d_in[6];
  const float* V2 = (const float*)d_in[7];
  const float* c2 = (const float*)d_in[8];
  const float* a0 = (const float*)d_in[9];
  float* out = (float*)d_out;

  dim3 blk(256);
  const size_t NEED_A = 252968960ull;  // bytes for layout A

  if (ws_size >= NEED_A) {
    // ---- Layout A: pre-split W2, DMA GEMM2 with fused norm ----
    char* base = (char*)d_ws;
    float* BLKT   = (float*)base;                      // 134217728 B
    float* VT     = (float*)(base + 134217728ull);     //  16777216 B
    f16*   W2hi   = (f16*)(base + 150994944ull);       //  33554432 B
    f16*   W2lo   = (f16*)(base + 184549376ull);       //  33554432 B
    f16*   H1hi   = (f16*)(base + 218103808ull);       //  16777216 B
    // H1lo lives at H1hi + M*N elements = base + 234881024
    unsigned* HVs = (unsigned*)(base + 218103808ull);  // alias (after MLP)
    float* Msum   = (float*)(base + 251658240ull);
    float* Csum   = (float*)(base + 252706816ull);
    float* Ybnd   = (float*)(base + 252837888ull);

    split_kernel<<<16384, blk, 0, stream>>>(W2, W2hi, W2lo, 16777216);
    for (int c = 0; c < 4; ++c) {
      const float* xc = x + (size_t)c * 2048 * 512;
      gemm_mfma<0, 4><<<dim3(32, 16), blk, 0, stream>>>(xc, W1, b1, H1hi, 2048, 4096, 512, 0);
      gemm2_dma<<<dim3(32, 16), blk, 0, stream>>>(
          H1hi, H1hi + (size_t)2048 * 4096, W2hi, W2lo, b2, BLKT,
          2048, 4096, 4096, c * 2048);
    }
    gemm_mfma<0, 0><<<dim3(4, 64), blk, 0, stream>>>(x, V1, c1, HVs, 8192, 512, 512, 0);
    gemm_mfma<1, 3><<<dim3(4, 64), blk, 0, stream>>>(HVs, V2, c2, VT, 8192, 512, 512, 0);
    scan_part1<<<1024, blk, 0, stream>>>(BLKT, VT, Msum, Csum);
    scan_part2<<<256, 64, 0, stream>>>(Msum, Csum, a0, Ybnd);
    scan_part3<<<1024, blk, 0, stream>>>(BLKT, VT, Ybnd, out);
  } else {
    // ---- Layout B: R5 fallback (known-safe 186 MB) ----
    float* ws = (float*)d_ws;
    float* BLKT = ws;
    float* VT   = ws + 33554432ull;
    unsigned* H1s = (unsigned*)(ws + 37748736ull);
    unsigned* HVs = H1s;
    float* Msum = ws + 46137344ull;
    float* Csum = ws + 46399488ull;
    float* Ybnd = ws + 46432256ull;

    for (int c = 0; c < 4; ++c) {
      const float* xc = x + (size_t)c * 2048 * 512;
      gemm_mfma<0, 0><<<dim3(32, 16), blk, 0, stream>>>(xc, W1, b1, H1s, 2048, 4096, 512, 0);
      gemm_mfma<1, 2><<<dim3(32, 16), blk, 0, stream>>>(H1s, W2, b2, BLKT, 2048, 4096, 4096, c * 2048);
    }
    norm_kernel<<<131072, blk, 0, stream>>>(BLKT);
    gemm_mfma<0, 0><<<dim3(4, 64), blk, 0, stream>>>(x, V1, c1, HVs, 8192, 512, 512, 0);
    gemm_mfma<1, 3><<<dim3(4, 64), blk, 0, stream>>>(HVs, V2, c2, VT, 8192, 512, 512, 0);
    scan_part1<<<1024, blk, 0, stream>>>(BLKT, VT, Msum, Csum);
    scan_part2<<<256, 64, 0, stream>>>(Msum, Csum, a0, Ybnd);
    scan_part3<<<1024, blk, 0, stream>>>(BLKT, VT, Ybnd, out);
  }
}